// Round 7
// baseline (60.341 us; speedup 1.0000x reference)
//
#include <hip/hip_runtime.h>

#define Hdim   128
#define Anodes 512
#define Bbatch 64
#define Eedges 16384
#define AMASK  (Anodes - 1)

// ws float offsets
#define WS_W1T 0        // bf16[128][128] stored as 8192 floats
#define WS_U   8192     // f32[512][128]

typedef __attribute__((ext_vector_type(8))) short short8;
typedef __attribute__((ext_vector_type(4))) float f32x4;

__device__ __forceinline__ short f2bf(float f) {
    union { float f; unsigned u; } v; v.f = f;
    unsigned r = v.u + 0x7FFFu + ((v.u >> 16) & 1u);
    return (short)(r >> 16);
}

// Single prep+aggregate kernel, 513 blocks:
//  block 0: cnt hist -> C = sum_{d:cnt>0} b2.wfc[d]; out[b] = bfc + C
//  blocks 1..512 (s = blk-1): per-block LDS hist of edges -> G[s,:] =
//    sum_d (pm[d]/max(cnt[d],1)) wfc[d,:] ; then U[s,k] = sum_h w2[k,h] G[s,h]
//  blocks 1..4 also transpose a 32-row strip of w1 into bf16 w1T (for k_main)
__global__ __launch_bounds__(256)
void k_Gall(const int* __restrict__ ei, const float* __restrict__ w1,
            const float* __restrict__ w2, const float* __restrict__ wfc,
            const float* __restrict__ b2, const float* __restrict__ bfc,
            float* __restrict__ ws, float* __restrict__ out) {
    __shared__ float w2L[Hdim][Hdim + 1];   // 66 KB; rows 0..31 double as transpose tile
    __shared__ unsigned cntL[Anodes];
    __shared__ unsigned pmL[Anodes];
    __shared__ unsigned short dlist[Anodes];
    __shared__ float plist[Anodes];
    __shared__ float Grow[Hdim];
    __shared__ float gred[Hdim];
    __shared__ int nz;

    const int tid = threadIdx.x;

    if (blockIdx.x == 0) {                   // C + out-init
        for (int i = tid; i < Anodes; i += 256) cntL[i] = 0;
        __syncthreads();
        for (int i = tid; i < Eedges; i += 256)
            atomicAdd(&cntL[ei[Eedges + i] & AMASK], 1u);
        __syncthreads();
        const int h = tid & 127, half = tid >> 7;
        const float bv = b2[h];
        float cp = 0.f;
        for (int d = half; d < Anodes; d += 2)
            if (cntL[d]) cp += bv * wfc[(size_t)d * Hdim + h];
        plist[tid] = cp;
        __syncthreads();
        for (int off = 128; off; off >>= 1) {
            if (tid < off) plist[tid] += plist[tid + off];
            __syncthreads();
        }
        if (tid < Bbatch) out[tid] = bfc[0] + plist[0];
        return;
    }

    const int s = blockIdx.x - 1;

    if (s < 4) {                             // w1T strip (extra duty)
        const int k0 = s * 32;
        for (int i = tid; i < 32 * 128; i += 256) {
            int r = i >> 7, c = i & 127;
            w2L[r][c] = w1[(k0 + r) * Hdim + c];
        }
        __syncthreads();
        short* o = (short*)(ws + WS_W1T);
        const int n = tid >> 1, j0 = (tid & 1) * 16;
        short tmp[16];
        #pragma unroll
        for (int j = 0; j < 16; ++j) tmp[j] = f2bf(w2L[j0 + j][n]);
        short8* dst = (short8*)(o + n * Hdim + k0 + j0);
        dst[0] = *(short8*)(tmp);
        dst[1] = *(short8*)(tmp + 8);
        __syncthreads();
    }

    // per-block histograms from raw edge list (no global state needed)
    for (int i = tid; i < Anodes; i += 256) { cntL[i] = 0; pmL[i] = 0; }
    if (tid == 0) nz = 0;
    __syncthreads();
    for (int i = tid; i < Eedges; i += 256) {
        int es = ei[i] & AMASK;
        int ed = ei[Eedges + i] & AMASK;
        atomicAdd(&cntL[ed], 1u);
        if (es == s) atomicAdd(&pmL[ed], 1u);
    }
    __syncthreads();
    // stage w2 rows (tile-reuse done; hist complete)
    for (int i = tid; i < Hdim * Hdim; i += 256)
        w2L[i >> 7][i & 127] = w2[i];
    // compress nonzero pm entries
    for (int d = tid; d < Anodes; d += 256) {
        unsigned p = pmL[d];
        if (p) {
            int slot = atomicAdd(&nz, 1);
            dlist[slot] = (unsigned short)d;
            plist[slot] = (float)p / fmaxf((float)cntL[d], 1.0f);
        }
    }
    __syncthreads();

    const int k = tid & 127, half = tid >> 7;
    const int n = nz;
    float g = 0.f;
    for (int i = half; i < n; i += 2)
        g += plist[i] * wfc[(size_t)dlist[i] * Hdim + k];
    if (half) gred[k] = g;
    __syncthreads();
    if (!half) Grow[k] = g + gred[k];
    __syncthreads();

    // U[s,k] = sum_h w2[k,h] * Grow[h]   (f32 exact)
    float u = 0.f;
    const int h0 = half * 64;
    #pragma unroll 8
    for (int hh = h0; hh < h0 + 64; ++hh) u += w2L[k][hh] * Grow[hh];
    if (half) gred[k] = u;
    __syncthreads();
    if (!half) ws[WS_U + (size_t)s * Hdim + k] = u + gred[k];
}

// MFMA: per block 64 rows; out[b] += sum_rows relu(x_row @ w1 + b1) . U[a,:]
__global__ __launch_bounds__(256)
void k_main(const float* __restrict__ x, const float* __restrict__ b1,
            const float* __restrict__ ws, float* __restrict__ out) {
    __shared__ short w1s[Hdim * Hdim];   // swizzled bf16 [n][k], 32 KB
    __shared__ float red[4];

    const int tid  = threadIdx.x;
    const int row0 = blockIdx.x * 64;
    const int b    = blockIdx.x >> 3;
    const int a0   = (blockIdx.x & 7) * 64;

    {
        const short8* gsrc = (const short8*)(ws + WS_W1T);
        for (int i = tid; i < 2048; i += 256) {
            short8 v = gsrc[i];
            int n = i >> 4;
            int byte = (i * 16) ^ ((n & 7) << 4);
            *(short8*)((char*)w1s + byte) = v;
        }
    }
    __syncthreads();

    const int w = tid >> 6;
    const int l = tid & 63;
    const int c = l & 15;
    const int g = l >> 4;

    const float* xrow = x + (size_t)(row0 + w * 16 + c) * Hdim;

    f32x4 acc[8];
    #pragma unroll
    for (int n = 0; n < 8; ++n) acc[n] = (f32x4){0.f, 0.f, 0.f, 0.f};

    #pragma unroll
    for (int ks = 0; ks < 4; ++ks) {
        const int k0 = ks * 32;
        float4 a_lo = *(const float4*)(xrow + k0 + 8 * g);
        float4 a_hi = *(const float4*)(xrow + k0 + 8 * g + 4);
        short8 a;
        a[0] = f2bf(a_lo.x); a[1] = f2bf(a_lo.y); a[2] = f2bf(a_lo.z); a[3] = f2bf(a_lo.w);
        a[4] = f2bf(a_hi.x); a[5] = f2bf(a_hi.y); a[6] = f2bf(a_hi.z); a[7] = f2bf(a_hi.w);
        #pragma unroll
        for (int n = 0; n < 8; ++n) {
            int byte = (((n * 16 + c) << 8) + ((k0 + 8 * g) << 1)) ^ ((c & 7) << 4);
            short8 bf = *(short8*)((char*)w1s + byte);
            acc[n] = __builtin_amdgcn_mfma_f32_16x16x32_bf16(a, bf, acc[n], 0, 0, 0);
        }
    }

    float part = 0.f;
    const float* U = ws + WS_U;
    #pragma unroll
    for (int n = 0; n < 8; ++n) {
        const int colg = n * 16 + c;
        const float bv = b1[colg];
        #pragma unroll
        for (int r = 0; r < 4; ++r) {
            const int arow = a0 + w * 16 + g * 4 + r;
            float z = acc[n][r] + bv;
            part += fmaxf(z, 0.f) * U[arow * Hdim + colg];
        }
    }
    #pragma unroll
    for (int off = 32; off; off >>= 1) part += __shfl_down(part, off, 64);
    if (l == 0) red[w] = part;
    __syncthreads();
    if (tid == 0) atomicAdd(out + b, red[0] + red[1] + red[2] + red[3]);
}

extern "C" void kernel_launch(void* const* d_in, const int* in_sizes, int n_in,
                              void* d_out, int out_size, void* d_ws, size_t ws_size,
                              hipStream_t stream) {
    const float* x   = (const float*)d_in[0];
    // d_in[1] = pos (unused)
    const int*   ei  = (const int*)d_in[2];
    const float* w1  = (const float*)d_in[3];
    const float* b1  = (const float*)d_in[4];
    const float* w2  = (const float*)d_in[5];
    const float* b2  = (const float*)d_in[6];
    const float* wfc = (const float*)d_in[7];
    const float* bfc = (const float*)d_in[8];
    float* out = (float*)d_out;
    float* ws  = (float*)d_ws;

    hipLaunchKernelGGL(k_Gall, dim3(513), dim3(256), 0, stream,
                       ei, w1, w2, wfc, b2, bfc, ws, out);
    hipLaunchKernelGGL(k_main, dim3(512), dim3(256), 0, stream, x, b1, ws, out);
}